// Round 8
// baseline (62.961 us; speedup 1.0000x reference)
//
#include <hip/hip_runtime.h>

#define ALPHA_C    0.5f
#define C_CLASSES  100000
#define D          128
#define BATCH      131072
#define CHUNK      2048
#define NB         ((C_CLASSES + CHUNK - 1) / CHUNK)   // 49 scan blocks

// ---------------------------------------------------------------------------
// DPP 32-lane group reduce (VALU-speed). After row_shr 1,2,4,8 each 16-row's
// lane15 holds the row sum; bcast15 (rmask 0xA: rows 1,3) adds row0->row1 and
// row2->row3. Lane 31 = sum of lanes 0..31, lane 63 = sum of lanes 32..63.
// ---------------------------------------------------------------------------
template<int CTRL, int RMASK>
__device__ __forceinline__ float dpp_add(float x) {
    int v = __builtin_amdgcn_update_dpp(0, __float_as_int(x), CTRL, RMASK, 0xF, true);
    return x + __int_as_float(v);
}
__device__ __forceinline__ float group_sum(float ss) {
    ss = dpp_add<0x111, 0xF>(ss);   // row_shr:1
    ss = dpp_add<0x112, 0xF>(ss);   // row_shr:2
    ss = dpp_add<0x114, 0xF>(ss);   // row_shr:4
    ss = dpp_add<0x118, 0xF>(ss);   // row_shr:8
    ss = dpp_add<0x142, 0xA>(ss);   // row_bcast15 -> rows 1,3
    return ss;                      // lane31 / lane63 hold the 32-lane sums
}

// ---------------------------------------------------------------------------
// K1: label histogram
// ---------------------------------------------------------------------------
__global__ void hist_kernel(const int* __restrict__ labels,
                            int* __restrict__ counts) {
    int i = blockIdx.x * blockDim.x + threadIdx.x;   // grid == BATCH exactly
    atomicAdd(&counts[labels[i]], 1);
}

// ---------------------------------------------------------------------------
// K2: per-chunk exclusive scan of counts; writes {chunk_excl, count} pairs
// ---------------------------------------------------------------------------
__global__ __launch_bounds__(256)
void scan1_kernel(const int* __restrict__ counts,
                  int2* __restrict__ co,
                  int* __restrict__ blockSums) {
    __shared__ int sdata[256];
    const int tid  = threadIdx.x;
    const int base = blockIdx.x * CHUNK + tid * 8;
    int v[8]; int s = 0;
    #pragma unroll
    for (int j = 0; j < 8; ++j) {
        int idx = base + j;
        v[j] = (idx < C_CLASSES) ? counts[idx] : 0;
        s += v[j];
    }
    sdata[tid] = s;
    __syncthreads();
    #pragma unroll
    for (int off = 1; off < 256; off <<= 1) {
        int t = (tid >= off) ? sdata[tid - off] : 0;
        __syncthreads();
        sdata[tid] += t;
        __syncthreads();
    }
    int excl = sdata[tid] - s;
    #pragma unroll
    for (int j = 0; j < 8; ++j) {
        int idx = base + j;
        if (idx < C_CLASSES) co[idx] = make_int2(excl, v[j]);
        excl += v[j];
    }
    if (tid == 255) blockSums[blockIdx.x] = sdata[255];
}

// ---------------------------------------------------------------------------
// K3: single-wave scan of the 49 chunk totals
// ---------------------------------------------------------------------------
__global__ void scan2_kernel(const int* __restrict__ blockSums,
                             int* __restrict__ blockOffsets) {
    const int lane = threadIdx.x;
    int v = (lane < NB) ? blockSums[lane] : 0;
    int incl = v;
    #pragma unroll
    for (int off = 1; off < 64; off <<= 1) {
        int t = __shfl_up(incl, off);
        if (lane >= off) incl += t;
    }
    blockOffsets[lane] = incl - v;
}

// ---------------------------------------------------------------------------
// K4: finalize offsets in co.x; seed scatter cursor
// ---------------------------------------------------------------------------
__global__ void addoff_kernel(int2* __restrict__ co,
                              const int* __restrict__ blockOffsets,
                              int* __restrict__ cursor) {
    int i = blockIdx.x * blockDim.x + threadIdx.x;
    if (i < C_CLASSES) {
        int f = co[i].x + blockOffsets[i / CHUNK];
        co[i].x = f;
        cursor[i] = f;
    }
}

// ---------------------------------------------------------------------------
// K5: scatter sample indices into class buckets
// ---------------------------------------------------------------------------
__global__ void scatter_kernel(const int* __restrict__ labels,
                               int* __restrict__ cursor,
                               int* __restrict__ order) {
    int b = blockIdx.x * blockDim.x + threadIdx.x;   // grid == BATCH exactly
    int pos = atomicAdd(&cursor[labels[b]], 1);
    order[pos] = b;
}

// ---------------------------------------------------------------------------
// K6 (R8): fused dim-major kernel. One 32-lane GROUP per class: lane t owns
// dims [4t,4t+4) as float4. 2 classes per wave -> 50K waves (2x TLP of R7),
// and every row access is ONE dwordx4 instruction per group:
//   co[c] broadcast -> center row (float4) -> per sample: order broadcast +
//   feature row (float4) -> acc += (f-c); ss = dot -> 5-DPP group reduce ->
//   lane31/63 stores result[b]; epilogue: one float4 row store.
// Vector-instruction count drops ~650K -> ~435K; dependent chain per wave
// is short (typically 1-2 samples); no cross-group machinery.
// ---------------------------------------------------------------------------
__global__ __launch_bounds__(256)
void fused_kernel(const float* __restrict__ features,
                  const float* __restrict__ centers,
                  const int2*  __restrict__ co,
                  const int*   __restrict__ order,
                  float* __restrict__ result,
                  float* __restrict__ out_centers) {
    const int wave = threadIdx.x >> 6;
    const int lane = threadIdx.x & 63;
    const int t    = lane & 31;                       // dim-quad index
    const int c    = (blockIdx.x * 4 + wave) * 2 + (lane >> 5);  // grid exact

    const int2 m    = co[c];                          // group-broadcast load
    const int start = m.x;
    const int n     = m.y;

    const float4 cv = ((const float4*)(centers + (size_t)c * D))[t];

    float ax = 0.f, ay = 0.f, az = 0.f, aw = 0.f;
    for (int j = 0; j < n; ++j) {
        const int b = order[start + j];               // group-uniform broadcast
        const float4 f = ((const float4*)(features + (size_t)b * D))[t];
        const float dx = f.x - cv.x, dy = f.y - cv.y;
        const float dz = f.z - cv.z, dw = f.w - cv.w;
        ax += dx; ay += dy; az += dz; aw += dw;
        const float ss = group_sum(dx * dx + dy * dy + dz * dz + dw * dw);
        if (t == 31) result[b] = ss;                  // lane31 (g0) / lane63 (g1)
    }

    const float inv = ALPHA_C / (1.0f + (float)n);
    float4 o;
    o.x = cv.x + ax * inv;
    o.y = cv.y + ay * inv;
    o.z = cv.z + az * inv;
    o.w = cv.w + aw * inv;
    ((float4*)(out_centers + (size_t)c * D))[t] = o;
}

// ---------------------------------------------------------------------------
extern "C" void kernel_launch(void* const* d_in, const int* in_sizes, int n_in,
                              void* d_out, int out_size, void* d_ws, size_t ws_size,
                              hipStream_t stream) {
    const float* features = (const float*)d_in[0];
    const int*   labels   = (const int*)d_in[1];
    const float* centers  = (const float*)d_in[2];

    float* result      = (float*)d_out;          // [BATCH]
    float* out_centers = result + BATCH;         // [C_CLASSES * D]

    int*  ws           = (int*)d_ws;             // ~2.1 MB total scratch
    int*  counts       = ws;                     // C
    int2* co           = (int2*)(ws + C_CLASSES);        // 2C ints
    int*  cursor       = ws + 3 * C_CLASSES;     // C
    int*  blockSums    = ws + 4 * C_CLASSES;     // 64
    int*  blockOffsets = blockSums + 64;         // 64
    int*  order        = blockOffsets + 64;      // BATCH

    (void)hipMemsetAsync(counts, 0, C_CLASSES * sizeof(int), stream);

    hist_kernel   <<<BATCH / 256, 256, 0, stream>>>(labels, counts);
    scan1_kernel  <<<NB,          256, 0, stream>>>(counts, co, blockSums);
    scan2_kernel  <<<1,            64, 0, stream>>>(blockSums, blockOffsets);
    addoff_kernel <<<(C_CLASSES + 255) / 256, 256, 0, stream>>>(co, blockOffsets, cursor);
    scatter_kernel<<<BATCH / 256, 256, 0, stream>>>(labels, cursor, order);

    fused_kernel  <<<C_CLASSES / 8, 256, 0, stream>>>(
        features, centers, co, order, result, out_centers);
}